// Round 13
// baseline (176.754 us; speedup 1.0000x reference)
//
#include <hip/hip_runtime.h>

typedef __bf16 bf16;
typedef __bf16 bf16x4 __attribute__((ext_vector_type(4)));
typedef __bf16 bf16x8 __attribute__((ext_vector_type(8)));
typedef float  f32x4  __attribute__((ext_vector_type(4)));

#define MFMA16(a, b, c) __builtin_amdgcn_mfma_f32_16x16x32_bf16((a), (b), (c), 0, 0, 0)

// R13 = R12's single-pass structure with the s2 matvec done BY MFMA (no global
// loads, no fp32 W2 array in the loop -- the R9/R12 spill source):
//  * s2 = W2·sumMu via B-frag with sumMu-HI in col k=0 and sumMu-LO in col k=1
//    (bf16 split, cndmask on l15). 4 chained MFMAs per qt (w2h/w2l x 2 halves):
//    D col0=(W2)·Sh, col1=(W2)·Sl at lanes l15∈{0,1}; s2q = shfl(quad*16)
//    + shfl(quad*16+1). Error ~2^-18 -> absmax 262144-class (R12-verified math).
//  * 80 MFMAs/iter total (R11: 192), mu read ONCE (16 b128; R11: 32).
//  * Main MFMAs independent of the s2 chain -> overlap.
//  * All loop transients are MFMA fragments (AGPR-side). RULE (R9/R12 autopsy):
//    fp32 global matvec in-loop => arch-VGPR spill; MFMA-side never spilled.
// LAUNCH-BOUNDS RULE (R2/R4/R8): never min-waves>2. SPILL TRIPWIRE:
// FETCH>>2.5MB or WRITE>>2KB => back off to R11.
__global__ __launch_bounds__(64, 2)
void qnet_kernel(const float* __restrict__ Xg, const float* __restrict__ Wg,
                 const float* __restrict__ W1g, const float* __restrict__ W2g,
                 const float* __restrict__ W3g, const float* __restrict__ W4g,
                 const float* __restrict__ W5g, const float* __restrict__ W6g,
                 const float* __restrict__ W7g, float* __restrict__ Outg)
{
    __shared__ __align__(16) bf16 muS[128 * 64];   // 16384 B, packed + swizzled
    __shared__ __align__(16) float uS[64];         // 256 B
    __shared__ __align__(16) float smS[64];        // 256 B  sumMu broadcast

    const int lane = threadIdx.x;       // 0..63, one wave
    const int b    = blockIdx.x;
    const int l15  = lane & 15;
    const int quad = lane >> 4;
    const int sw   = l15 & 7;           // swizzle key: k&7 == l15&7 for k=16kt+l15

    // ---------------- per-batch vectors (registers only) ----------------
    float xv0 = Xg[b * 128 + lane], xv1 = Xg[b * 128 + 64 + lane];
    float wv0 = Wg[b * 128 + lane], wv1 = Wg[b * 128 + 64 + lane];

    float Ap = fmaxf(wv0, 0.f) + fmaxf(wv1, 0.f);
    float Bn = fmaxf(-wv0, 0.f) + fmaxf(-wv1, 0.f);
#pragma unroll
    for (int m = 1; m < 64; m <<= 1) { Ap += __shfl_xor(Ap, m); Bn += __shfl_xor(Bn, m); }

    // per-kt scalars via shfl (k = kt*16 + l15)
    float xk[8], apk[8], bnk[8];
#pragma unroll
    for (int kt = 0; kt < 8; ++kt) {
        const int src = (kt & 3) * 16 + l15;
        float xs_ = (kt < 4) ? __shfl(xv0, src) : __shfl(xv1, src);
        float ws_ = (kt < 4) ? __shfl(wv0, src) : __shfl(wv1, src);
        xk[kt]  = xs_;
        apk[kt] = Ap - fmaxf(ws_, 0.f);
        bnk[kt] = Bn - fmaxf(-ws_, 0.f);
    }

    // v3p/v3m at q=lane (exact fp32), distribute to (qt,e) epilogue layout
    float sp = 0.f, sm = 0.f;
#pragma unroll
    for (int c = 0; c < 16; ++c) {
        f32x4 w4 = *(const f32x4*)&W4g[c * 4];
        f32x4 w3 = *(const f32x4*)&W3g[lane * 64 + c * 4];
#pragma unroll
        for (int e = 0; e < 4; ++e) {
            sp += fmaxf(w4[e], 0.f) * w3[e];
            sm += fmaxf(-w4[e], 0.f) * w3[e];
        }
    }
    float w1C[16], v3pC[16], v3mC[16];
#pragma unroll
    for (int qt = 0; qt < 4; ++qt) {
        f32x4 w1v = *(const f32x4*)&W1g[qt * 16 + quad * 4];
#pragma unroll
        for (int e = 0; e < 4; ++e) {
            const int q = qt * 16 + quad * 4 + e;
            v3pC[qt * 4 + e] = __shfl(sp, q);
            v3mC[qt * 4 + e] = __shfl(sm, q);
            w1C[qt * 4 + e]  = w1v[e];
        }
    }

    // u[p=lane] = W5b @ W7[:,p] -> uS (wave-private LDS)
    {
        float u = 0.f;
#pragma unroll
        for (int c = 0; c < 16; ++c) {
            f32x4 w5v = *(const f32x4*)&W5g[64 + c * 4];
#pragma unroll
            for (int e = 0; e < 4; ++e) u += w5v[e] * W7g[(c * 4 + e) * 64 + lane];
        }
        uS[lane] = u;
    }

    // W2 A-fragments hi+lo (AGPR-side residents; R11 fit at 116 with both)
    bf16x8 w2h[4][2], w2l[4][2];
#pragma unroll
    for (int qt = 0; qt < 4; ++qt)
#pragma unroll
        for (int s = 0; s < 2; ++s) {
            const float* src = &W2g[(qt * 16 + l15) * 64 + s * 32 + quad * 8];
            f32x4 f0 = *(const f32x4*)src;
            f32x4 f1 = *(const f32x4*)(src + 4);
            bf16x8 h, l;
#pragma unroll
            for (int e = 0; e < 4; ++e) {
                bf16 h0 = (bf16)f0[e], h1 = (bf16)f1[e];
                h[e] = h0; h[4 + e] = h1;
                l[e]     = (bf16)(f0[e] - (float)h0);
                l[4 + e] = (bf16)(f1[e] - (float)h1);
            }
            w2h[qt][s] = h; w2l[qt][s] = l;
        }

    // ---------------- mu1 = relu(base), exact fp32; accumulate smv ----------------
    float smv[16];
#pragma unroll
    for (int i = 0; i < 16; ++i) smv[i] = 0.f;
#pragma unroll
    for (int kt = 0; kt < 8; ++kt) {
        const int row = (kt * 16 + l15) * 64;
#pragma unroll
        for (int qt = 0; qt < 4; ++qt) {
            bf16x4 h;
#pragma unroll
            for (int e = 0; e < 4; ++e) {
                float t = fmaf(xk[kt], w1C[qt * 4 + e],
                          fmaf(apk[kt], v3pC[qt * 4 + e], bnk[kt] * v3mC[qt * 4 + e]));
                float v = fmaxf(t, 0.f);
                smv[qt * 4 + e] += v;
                h[e] = (bf16)v;
            }
            *(bf16x4*)&muS[row + ((2 * qt + (quad >> 1)) ^ sw) * 8 + 4 * (quad & 1)] = h;
        }
    }

    // ---------------- 3 iterations, zero barriers ----------------
    const f32x4 zero4 = {0.f, 0.f, 0.f, 0.f};
    const bf16x8 zero8 = {(bf16)0.f,(bf16)0.f,(bf16)0.f,(bf16)0.f,
                          (bf16)0.f,(bf16)0.f,(bf16)0.f,(bf16)0.f};
    for (int it = 0; it < 3; ++it) {
        // sumMu: l15 butterfly + publish to smS
#pragma unroll
        for (int m = 1; m <= 8; m <<= 1)
#pragma unroll
            for (int i = 0; i < 16; ++i) smv[i] += __shfl_xor(smv[i], m);
        if (l15 == 0) {
#pragma unroll
            for (int qt = 0; qt < 4; ++qt) {
                f32x4 v = {smv[qt * 4], smv[qt * 4 + 1], smv[qt * 4 + 2], smv[qt * 4 + 3]};
                *(f32x4*)&smS[qt * 16 + quad * 4] = v;
            }
        }
        // s2 = W2·sumMu by MFMA: B-frag has Sh in col k=0, Sl in col k=1.
        // Every lane reads its p-slice (p = s*32 + quad*8 + j), splits hi/lo.
        bf16x8 bs0, bs1;
        {
            f32x4 p00 = *(const f32x4*)&smS[quad * 8];
            f32x4 p01 = *(const f32x4*)&smS[quad * 8 + 4];
            f32x4 p10 = *(const f32x4*)&smS[32 + quad * 8];
            f32x4 p11 = *(const f32x4*)&smS[32 + quad * 8 + 4];
            bf16x8 h0, l0, h1, l1;
#pragma unroll
            for (int e = 0; e < 4; ++e) {
                bf16 a = (bf16)p00[e], c = (bf16)p01[e];
                h0[e] = a; h0[4 + e] = c;
                l0[e]     = (bf16)(p00[e] - (float)a);
                l0[4 + e] = (bf16)(p01[e] - (float)c);
                bf16 d = (bf16)p10[e], f = (bf16)p11[e];
                h1[e] = d; h1[4 + e] = f;
                l1[e]     = (bf16)(p10[e] - (float)d);
                l1[4 + e] = (bf16)(p11[e] - (float)f);
            }
            bs0 = (l15 == 0) ? h0 : ((l15 == 1) ? l0 : zero8);
            bs1 = (l15 == 0) ? h1 : ((l15 == 1) ? l1 : zero8);
        }
        f32x4 s2q[4];
#pragma unroll
        for (int qt = 0; qt < 4; ++qt) {
            f32x4 a = MFMA16(w2h[qt][0], bs0, zero4);
            a = MFMA16(w2h[qt][1], bs1, a);
            a = MFMA16(w2l[qt][0], bs0, a);
            a = MFMA16(w2l[qt][1], bs1, a);
            // s2[q=qt*16+quad*4+e] = col0 + col1 = lanes (quad*16) and (quad*16+1)
#pragma unroll
            for (int e = 0; e < 4; ++e)
                s2q[qt][e] = __shfl(a[e], quad * 16) + __shfl(a[e], quad * 16 + 1);
        }

        // main pass: 64 MFMAs + fused epilogue (base recomputed fp32-exact)
#pragma unroll
        for (int i = 0; i < 16; ++i) smv[i] = 0.f;
#pragma unroll
        for (int kt = 0; kt < 8; ++kt) {
            const int row = (kt * 16 + l15) * 64;
            bf16x8 m0 = *(const bf16x8*)&muS[row + ((quad) ^ sw) * 8];
            bf16x8 m1 = *(const bf16x8*)&muS[row + ((4 + quad) ^ sw) * 8];
#pragma unroll
            for (int qt = 0; qt < 4; ++qt) {
                f32x4 a = MFMA16(w2h[qt][0], m0, zero4);
                a = MFMA16(w2h[qt][1], m1, a);
                bf16x4 h;
#pragma unroll
                for (int e = 0; e < 4; ++e) {
                    float t = fmaf(xk[kt], w1C[qt * 4 + e], s2q[qt][e]);
                    t = fmaf(apk[kt], v3pC[qt * 4 + e], t);
                    t = fmaf(bnk[kt], v3mC[qt * 4 + e], t);
                    float v = fmaxf(t - a[e], 0.f);
                    smv[qt * 4 + e] += v;
                    h[e] = (bf16)v;
                }
                *(bf16x4*)&muS[row + ((2 * qt + (quad >> 1)) ^ sw) * 8 + 4 * (quad & 1)] = h;
            }
        }
    }

    // ---------------- readout (wave-internal) ----------------
#pragma unroll
    for (int m = 1; m <= 8; m <<= 1)
#pragma unroll
        for (int i = 0; i < 16; ++i) smv[i] += __shfl_xor(smv[i], m);
    if (l15 == 0) {
#pragma unroll
        for (int qt = 0; qt < 4; ++qt) {
            f32x4 v = {smv[qt * 4], smv[qt * 4 + 1], smv[qt * 4 + 2], smv[qt * 4 + 3]};
            *(f32x4*)&smS[qt * 16 + quad * 4] = v;
        }
    }

    float pl = 0.f;
#pragma unroll
    for (int c = 0; c < 16; ++c) {
        f32x4 sv = *(const f32x4*)&smS[c * 4];
        f32x4 w6 = *(const f32x4*)&W6g[lane * 64 + c * 4];
#pragma unroll
        for (int e = 0; e < 4; ++e) pl = fmaf(sv[e], w6[e], pl);
    }
    float qa = fmaxf(pl, 0.f) * W5g[lane];
#pragma unroll
    for (int m = 1; m < 64; m <<= 1) qa += __shfl_xor(qa, m);

    f32x4 uf[2][2];
#pragma unroll
    for (int s = 0; s < 2; ++s) {
        uf[s][0] = *(const f32x4*)&uS[s * 32 + quad * 8];
        uf[s][1] = *(const f32x4*)&uS[s * 32 + quad * 8 + 4];
    }

    float res[8];
#pragma unroll
    for (int kt = 0; kt < 8; ++kt) {
        const int row = (kt * 16 + l15) * 64;
        bf16x8 m0 = *(const bf16x8*)&muS[row + ((quad) ^ sw) * 8];
        bf16x8 m1 = *(const bf16x8*)&muS[row + ((4 + quad) ^ sw) * 8];
        float r = 0.f;
#pragma unroll
        for (int j = 0; j < 4; ++j) {
            r = fmaf((float)m0[j],     uf[0][0][j], r);
            r = fmaf((float)m0[4 + j], uf[0][1][j], r);
            r = fmaf((float)m1[j],     uf[1][0][j], r);
            r = fmaf((float)m1[4 + j], uf[1][1][j], r);
        }
        r += __shfl_xor(r, 16); r += __shfl_xor(r, 32);
        res[kt] = r;
    }
    float rA0 = (quad & 1) ? res[1] : res[0];
    float rA1 = (quad & 1) ? res[3] : res[2];
    float rA  = (quad & 2) ? rA1 : rA0;
    float rB0 = (quad & 1) ? res[5] : res[4];
    float rB1 = (quad & 1) ? res[7] : res[6];
    float rB  = (quad & 2) ? rB1 : rB0;
    Outg[b * 128 + lane]      = qa + rA;   // k = lane       (kt = quad)
    Outg[b * 128 + 64 + lane] = qa + rB;   // k = lane + 64  (kt = quad + 4)
}

extern "C" void kernel_launch(void* const* d_in, const int* in_sizes, int n_in,
                              void* d_out, int out_size, void* d_ws, size_t ws_size,
                              hipStream_t stream) {
    (void)n_in; (void)d_ws; (void)ws_size; (void)out_size;
    const int B = in_sizes[0] >> 7;   // 4096
    qnet_kernel<<<B, 64, 0, stream>>>(
        (const float*)d_in[0], (const float*)d_in[1], (const float*)d_in[2],
        (const float*)d_in[3], (const float*)d_in[4], (const float*)d_in[5],
        (const float*)d_in[6], (const float*)d_in[7], (const float*)d_in[8],
        (float*)d_out);
}

// Round 14
// 164.886 us; speedup vs baseline: 1.0720x; 1.0720x over previous
//
#include <hip/hip_runtime.h>

typedef __bf16 bf16;
typedef __bf16 bf16x4 __attribute__((ext_vector_type(4)));
typedef __bf16 bf16x8 __attribute__((ext_vector_type(8)));
typedef float  f32x4  __attribute__((ext_vector_type(4)));

#define MFMA16(a, b, c) __builtin_amdgcn_mfma_f32_16x16x32_bf16((a), (b), (c), 0, 0, 0)

// R14: DUAL-BATCH PER WAVE. One 64-lane wave processes TWO batch elements,
// interleaved at the kt level, zero barriers (R11 machinery verbatim per batch).
// Rationale (R11 counters): wave is ~70% stalled on serial chains (LDS 120cyc,
// shfl butterflies, MFMA dep chains) at only 2.25 waves/SIMD. Dual-batch fills
// stalls IN-STREAM: b0's chains overlap b1's independent work.
//  * Shared across batches: w2h/w2l A-frags, w1C/v3pC/v3mC consts, uS (~80 regs
//    + weights fetched once per 2 batches -> FETCH halves).
//  * Per-batch: xk/apk/bnk, smv, rs (~56 regs x2). Total ~200 < 256: no squeeze.
//  * LDS 2x16.4KB muS + 2x smS + uS = 33.5KB -> 4 blocks/CU = 1 wave/SIMD;
//    latency hiding now comes from dual-stream ILP instead of TLP.
// SPILL HISTORY (R2/R4/R8 launch-bounds; R9/R12/R13 in-loop transients):
// tripwire = FETCH >> 1.5MB or WRITE >> 2.5MB => revert to R11.
__global__ __launch_bounds__(64, 1)
void qnet_kernel(const float* __restrict__ Xg, const float* __restrict__ Wg,
                 const float* __restrict__ W1g, const float* __restrict__ W2g,
                 const float* __restrict__ W3g, const float* __restrict__ W4g,
                 const float* __restrict__ W5g, const float* __restrict__ W6g,
                 const float* __restrict__ W7g, float* __restrict__ Outg)
{
    __shared__ __align__(16) bf16 muS[2][128 * 64];  // 32768 B, packed + swizzled
    __shared__ __align__(16) float uS[64];           // 256 B (shared: weights only)
    __shared__ __align__(16) float smS[2][64];       // 512 B sumMu broadcast per batch

    const int lane = threadIdx.x;       // 0..63, one wave
    const int b0   = blockIdx.x * 2;
    const int l15  = lane & 15;
    const int quad = lane >> 4;
    const int sw   = l15 & 7;           // swizzle key: k&7 == l15&7 for k=16kt+l15

    // ---------------- per-batch vectors (both batches) ----------------
    float xk[2][8], apk[2][8], bnk[2][8];
#pragma unroll
    for (int u = 0; u < 2; ++u) {
        const int b = b0 + u;
        float xv0 = Xg[b * 128 + lane], xv1 = Xg[b * 128 + 64 + lane];
        float wv0 = Wg[b * 128 + lane], wv1 = Wg[b * 128 + 64 + lane];
        float Ap = fmaxf(wv0, 0.f) + fmaxf(wv1, 0.f);
        float Bn = fmaxf(-wv0, 0.f) + fmaxf(-wv1, 0.f);
#pragma unroll
        for (int m = 1; m < 64; m <<= 1) { Ap += __shfl_xor(Ap, m); Bn += __shfl_xor(Bn, m); }
#pragma unroll
        for (int kt = 0; kt < 8; ++kt) {
            const int src = (kt & 3) * 16 + l15;
            float xs_ = (kt < 4) ? __shfl(xv0, src) : __shfl(xv1, src);
            float ws_ = (kt < 4) ? __shfl(wv0, src) : __shfl(wv1, src);
            xk[u][kt]  = xs_;
            apk[u][kt] = Ap - fmaxf(ws_, 0.f);
            bnk[u][kt] = Bn - fmaxf(-ws_, 0.f);
        }
    }

    // v3p/v3m at q=lane (exact fp32, shared), distribute to (qt,e) layout
    float sp = 0.f, sm = 0.f;
#pragma unroll
    for (int c = 0; c < 16; ++c) {
        f32x4 w4 = *(const f32x4*)&W4g[c * 4];
        f32x4 w3 = *(const f32x4*)&W3g[lane * 64 + c * 4];
#pragma unroll
        for (int e = 0; e < 4; ++e) {
            sp += fmaxf(w4[e], 0.f) * w3[e];
            sm += fmaxf(-w4[e], 0.f) * w3[e];
        }
    }
    float w1C[16], v3pC[16], v3mC[16];
#pragma unroll
    for (int qt = 0; qt < 4; ++qt) {
        f32x4 w1v = *(const f32x4*)&W1g[qt * 16 + quad * 4];
#pragma unroll
        for (int e = 0; e < 4; ++e) {
            const int q = qt * 16 + quad * 4 + e;
            v3pC[qt * 4 + e] = __shfl(sp, q);
            v3mC[qt * 4 + e] = __shfl(sm, q);
            w1C[qt * 4 + e]  = w1v[e];
        }
    }

    // u[p=lane] = W5b @ W7[:,p] -> uS (shared)
    {
        float u = 0.f;
#pragma unroll
        for (int c = 0; c < 16; ++c) {
            f32x4 w5v = *(const f32x4*)&W5g[64 + c * 4];
#pragma unroll
            for (int e = 0; e < 4; ++e) u += w5v[e] * W7g[(c * 4 + e) * 64 + lane];
        }
        uS[lane] = u;
    }

    // W2 A-fragments hi+lo (shared, AGPR-side)
    bf16x8 w2h[4][2], w2l[4][2];
#pragma unroll
    for (int qt = 0; qt < 4; ++qt)
#pragma unroll
        for (int s = 0; s < 2; ++s) {
            const float* src = &W2g[(qt * 16 + l15) * 64 + s * 32 + quad * 8];
            f32x4 f0 = *(const f32x4*)src;
            f32x4 f1 = *(const f32x4*)(src + 4);
            bf16x8 h, l;
#pragma unroll
            for (int e = 0; e < 4; ++e) {
                bf16 h0 = (bf16)f0[e], h1 = (bf16)f1[e];
                h[e] = h0; h[4 + e] = h1;
                l[e]     = (bf16)(f0[e] - (float)h0);
                l[4 + e] = (bf16)(f1[e] - (float)h1);
            }
            w2h[qt][s] = h; w2l[qt][s] = l;
        }

    // ---------------- mu1 = relu(base), exact fp32 (both batches) ----------------
#pragma unroll
    for (int kt = 0; kt < 8; ++kt) {
        const int row = (kt * 16 + l15) * 64;
#pragma unroll
        for (int u = 0; u < 2; ++u)
#pragma unroll
            for (int qt = 0; qt < 4; ++qt) {
                bf16x4 h;
#pragma unroll
                for (int e = 0; e < 4; ++e) {
                    float t = fmaf(xk[u][kt], w1C[qt * 4 + e],
                              fmaf(apk[u][kt], v3pC[qt * 4 + e], bnk[u][kt] * v3mC[qt * 4 + e]));
                    h[e] = (bf16)fmaxf(t, 0.f);
                }
                *(bf16x4*)&muS[u][row + ((2 * qt + (quad >> 1)) ^ sw) * 8 + 4 * (quad & 1)] = h;
            }
    }

    // ---------------- 3 iterations, zero barriers, dual-stream ----------------
    const f32x4 zero4 = {0.f, 0.f, 0.f, 0.f};
    float smv[2][16];
    for (int it = 0; it < 3; ++it) {
        // pass1: s2 rowsums for BOTH batches, kt-interleaved (hi+lo)
        f32x4 rs0[4] = {zero4, zero4, zero4, zero4};
        f32x4 rs1[4] = {zero4, zero4, zero4, zero4};
#pragma unroll
        for (int kt = 0; kt < 8; ++kt) {
            const int row = (kt * 16 + l15) * 64;
            bf16x8 a0 = *(const bf16x8*)&muS[0][row + ((quad) ^ sw) * 8];
            bf16x8 a1 = *(const bf16x8*)&muS[0][row + ((4 + quad) ^ sw) * 8];
            bf16x8 b0v = *(const bf16x8*)&muS[1][row + ((quad) ^ sw) * 8];
            bf16x8 b1v = *(const bf16x8*)&muS[1][row + ((4 + quad) ^ sw) * 8];
#pragma unroll
            for (int qt = 0; qt < 4; ++qt) {
                f32x4 pa = MFMA16(w2h[qt][0], a0, zero4);
                pa = MFMA16(w2h[qt][1], a1, pa);
                f32x4 qa_ = MFMA16(w2l[qt][0], a0, zero4);
                qa_ = MFMA16(w2l[qt][1], a1, qa_);
                rs0[qt] += pa + qa_;
                f32x4 pb = MFMA16(w2h[qt][0], b0v, zero4);
                pb = MFMA16(w2h[qt][1], b1v, pb);
                f32x4 qb = MFMA16(w2l[qt][0], b0v, zero4);
                qb = MFMA16(w2l[qt][1], b1v, qb);
                rs1[qt] += pb + qb;
            }
        }
        // butterflies (independent chains interleave)
#pragma unroll
        for (int m = 1; m <= 8; m <<= 1)
#pragma unroll
            for (int qt = 0; qt < 4; ++qt)
#pragma unroll
                for (int e = 0; e < 4; ++e) {
                    rs0[qt][e] += __shfl_xor(rs0[qt][e], m);
                    rs1[qt][e] += __shfl_xor(rs1[qt][e], m);
                }

        // pass2: recompute acc (hi) + fused epilogue, both batches per kt
#pragma unroll
        for (int kt = 0; kt < 8; ++kt) {
            const int row = (kt * 16 + l15) * 64;
            bf16x8 a0 = *(const bf16x8*)&muS[0][row + ((quad) ^ sw) * 8];
            bf16x8 a1 = *(const bf16x8*)&muS[0][row + ((4 + quad) ^ sw) * 8];
            bf16x8 b0v = *(const bf16x8*)&muS[1][row + ((quad) ^ sw) * 8];
            bf16x8 b1v = *(const bf16x8*)&muS[1][row + ((4 + quad) ^ sw) * 8];
#pragma unroll
            for (int qt = 0; qt < 4; ++qt) {
                f32x4 aa = MFMA16(w2h[qt][0], a0, zero4);
                aa = MFMA16(w2h[qt][1], a1, aa);
                f32x4 ab = MFMA16(w2h[qt][0], b0v, zero4);
                ab = MFMA16(w2h[qt][1], b1v, ab);
                bf16x4 ha, hb;
#pragma unroll
                for (int e = 0; e < 4; ++e) {
                    float t = fmaf(xk[0][kt], w1C[qt * 4 + e], rs0[qt][e]);
                    t = fmaf(apk[0][kt], v3pC[qt * 4 + e], t);
                    t = fmaf(bnk[0][kt], v3mC[qt * 4 + e], t);
                    float v = fmaxf(t - aa[e], 0.f);
                    ha[e] = (bf16)v;
                    float t2 = fmaf(xk[1][kt], w1C[qt * 4 + e], rs1[qt][e]);
                    t2 = fmaf(apk[1][kt], v3pC[qt * 4 + e], t2);
                    t2 = fmaf(bnk[1][kt], v3mC[qt * 4 + e], t2);
                    float v2 = fmaxf(t2 - ab[e], 0.f);
                    hb[e] = (bf16)v2;
                    if (it == 2) { smv[0][qt * 4 + e] = (kt == 0 ? v : smv[0][qt * 4 + e] + v);
                                   smv[1][qt * 4 + e] = (kt == 0 ? v2 : smv[1][qt * 4 + e] + v2); }
                }
                *(bf16x4*)&muS[0][row + ((2 * qt + (quad >> 1)) ^ sw) * 8 + 4 * (quad & 1)] = ha;
                *(bf16x4*)&muS[1][row + ((2 * qt + (quad >> 1)) ^ sw) * 8 + 4 * (quad & 1)] = hb;
            }
        }
    }

    // ---------------- readout (both batches, wave-internal) ----------------
#pragma unroll
    for (int m = 1; m <= 8; m <<= 1)
#pragma unroll
        for (int i = 0; i < 16; ++i) {
            smv[0][i] += __shfl_xor(smv[0][i], m);
            smv[1][i] += __shfl_xor(smv[1][i], m);
        }
    if (l15 == 0) {
#pragma unroll
        for (int u = 0; u < 2; ++u)
#pragma unroll
            for (int qt = 0; qt < 4; ++qt) {
                f32x4 v = {smv[u][qt * 4], smv[u][qt * 4 + 1], smv[u][qt * 4 + 2], smv[u][qt * 4 + 3]};
                *(f32x4*)&smS[u][qt * 16 + quad * 4] = v;
            }
    }

    float pl0 = 0.f, pl1 = 0.f;
#pragma unroll
    for (int c = 0; c < 16; ++c) {
        f32x4 sv0 = *(const f32x4*)&smS[0][c * 4];
        f32x4 sv1 = *(const f32x4*)&smS[1][c * 4];
        f32x4 w6 = *(const f32x4*)&W6g[lane * 64 + c * 4];
#pragma unroll
        for (int e = 0; e < 4; ++e) { pl0 = fmaf(sv0[e], w6[e], pl0); pl1 = fmaf(sv1[e], w6[e], pl1); }
    }
    float w5a = W5g[lane];
    float qa0 = fmaxf(pl0, 0.f) * w5a;
    float qa1 = fmaxf(pl1, 0.f) * w5a;
#pragma unroll
    for (int m = 1; m < 64; m <<= 1) { qa0 += __shfl_xor(qa0, m); qa1 += __shfl_xor(qa1, m); }

    f32x4 uf[2][2];
#pragma unroll
    for (int s = 0; s < 2; ++s) {
        uf[s][0] = *(const f32x4*)&uS[s * 32 + quad * 8];
        uf[s][1] = *(const f32x4*)&uS[s * 32 + quad * 8 + 4];
    }

#pragma unroll
    for (int u = 0; u < 2; ++u) {
        float res[8];
#pragma unroll
        for (int kt = 0; kt < 8; ++kt) {
            const int row = (kt * 16 + l15) * 64;
            bf16x8 m0 = *(const bf16x8*)&muS[u][row + ((quad) ^ sw) * 8];
            bf16x8 m1 = *(const bf16x8*)&muS[u][row + ((4 + quad) ^ sw) * 8];
            float r = 0.f;
#pragma unroll
            for (int j = 0; j < 4; ++j) {
                r = fmaf((float)m0[j],     uf[0][0][j], r);
                r = fmaf((float)m0[4 + j], uf[0][1][j], r);
                r = fmaf((float)m1[j],     uf[1][0][j], r);
                r = fmaf((float)m1[4 + j], uf[1][1][j], r);
            }
            r += __shfl_xor(r, 16); r += __shfl_xor(r, 32);
            res[kt] = r;
        }
        float rA0 = (quad & 1) ? res[1] : res[0];
        float rA1 = (quad & 1) ? res[3] : res[2];
        float rA  = (quad & 2) ? rA1 : rA0;
        float rB0 = (quad & 1) ? res[5] : res[4];
        float rB1 = (quad & 1) ? res[7] : res[6];
        float rB  = (quad & 2) ? rB1 : rB0;
        float qa = u ? qa1 : qa0;
        Outg[(b0 + u) * 128 + lane]      = qa + rA;
        Outg[(b0 + u) * 128 + 64 + lane] = qa + rB;
    }
}

extern "C" void kernel_launch(void* const* d_in, const int* in_sizes, int n_in,
                              void* d_out, int out_size, void* d_ws, size_t ws_size,
                              hipStream_t stream) {
    (void)n_in; (void)d_ws; (void)ws_size; (void)out_size;
    const int B = in_sizes[0] >> 7;   // 4096
    qnet_kernel<<<B / 2, 64, 0, stream>>>(
        (const float*)d_in[0], (const float*)d_in[1], (const float*)d_in[2],
        (const float*)d_in[3], (const float*)d_in[4], (const float*)d_in[5],
        (const float*)d_in[6], (const float*)d_in[7], (const float*)d_in[8],
        (float*)d_out);
}

// Round 15
// 127.711 us; speedup vs baseline: 1.3840x; 1.2911x over previous
//
#include <hip/hip_runtime.h>

typedef __bf16 bf16;
typedef __bf16 bf16x4 __attribute__((ext_vector_type(4)));
typedef __bf16 bf16x8 __attribute__((ext_vector_type(8)));
typedef float  f32x4  __attribute__((ext_vector_type(4)));

#define MFMA16(a, b, c) __builtin_amdgcn_mfma_f32_16x16x32_bf16((a), (b), (c), 0, 0, 0)

// R15 = R11 frame (zero barriers, wave-per-b, 16.9KB LDS -> 9 waves/CU) with
// pass1 DELETED and s2 computed by the R13-verified sumMu-MFMA:
//  * smv (colsum of mu) accumulates in every epilogue (R12-verified), butterfly
//    -> smS publish -> B-frag with sumMu-HI in col n=0, LO in col n=1 ->
//    2 chained hi-W2 MFMAs per qt -> s2q = shfl(col0)+shfl(col1). R13 ran this
//    exact math correct on HW (absmax 262144); it spilled only because w2l(+32)
//    stayed live. Here pass1 is gone so w2l is DEAD: -32 regs pays for the ~32
//    scoped transients. Dropped w2l*sumMu term ~0.1 absolute: negligible.
//  * Per iter: 72 MFMAs (R11: 192), 16 mu b128 reads (R11: 32), 32 b64 writes.
//  * LDS/register budget = R11's proven config -> same 9 waves/CU occupancy.
// LAUNCH-BOUNDS RULE (R2/R4/R8): never min-waves>2. SPILL TRIPWIRE (R9/R12/R13):
// VGPR pinned 128 + FETCH>>2.5MB or WRITE>>2KB => transients overflowed => R11.
__global__ __launch_bounds__(64, 2)
void qnet_kernel(const float* __restrict__ Xg, const float* __restrict__ Wg,
                 const float* __restrict__ W1g, const float* __restrict__ W2g,
                 const float* __restrict__ W3g, const float* __restrict__ W4g,
                 const float* __restrict__ W5g, const float* __restrict__ W6g,
                 const float* __restrict__ W7g, float* __restrict__ Outg)
{
    __shared__ __align__(16) bf16 muS[128 * 64];   // 16384 B, packed + swizzled
    __shared__ __align__(16) float uS[64];         // 256 B
    __shared__ __align__(16) float smS[64];        // 256 B  sumMu broadcast

    const int lane = threadIdx.x;       // 0..63, one wave
    const int b    = blockIdx.x;
    const int l15  = lane & 15;
    const int quad = lane >> 4;
    const int sw   = l15 & 7;           // swizzle key: k&7 == l15&7 for k=16kt+l15

    // ---------------- per-batch vectors (registers only) ----------------
    float xv0 = Xg[b * 128 + lane], xv1 = Xg[b * 128 + 64 + lane];
    float wv0 = Wg[b * 128 + lane], wv1 = Wg[b * 128 + 64 + lane];

    float Ap = fmaxf(wv0, 0.f) + fmaxf(wv1, 0.f);
    float Bn = fmaxf(-wv0, 0.f) + fmaxf(-wv1, 0.f);
#pragma unroll
    for (int m = 1; m < 64; m <<= 1) { Ap += __shfl_xor(Ap, m); Bn += __shfl_xor(Bn, m); }

    // per-kt scalars via shfl (k = kt*16 + l15)
    float xk[8], apk[8], bnk[8];
#pragma unroll
    for (int kt = 0; kt < 8; ++kt) {
        const int src = (kt & 3) * 16 + l15;
        float xs_ = (kt < 4) ? __shfl(xv0, src) : __shfl(xv1, src);
        float ws_ = (kt < 4) ? __shfl(wv0, src) : __shfl(wv1, src);
        xk[kt]  = xs_;
        apk[kt] = Ap - fmaxf(ws_, 0.f);
        bnk[kt] = Bn - fmaxf(-ws_, 0.f);
    }

    // v3p/v3m at q=lane (exact fp32), distribute to (qt,e) epilogue layout
    float sp = 0.f, sm = 0.f;
#pragma unroll
    for (int c = 0; c < 16; ++c) {
        f32x4 w4 = *(const f32x4*)&W4g[c * 4];
        f32x4 w3 = *(const f32x4*)&W3g[lane * 64 + c * 4];
#pragma unroll
        for (int e = 0; e < 4; ++e) {
            sp += fmaxf(w4[e], 0.f) * w3[e];
            sm += fmaxf(-w4[e], 0.f) * w3[e];
        }
    }
    float w1C[16], v3pC[16], v3mC[16];
#pragma unroll
    for (int qt = 0; qt < 4; ++qt) {
        f32x4 w1v = *(const f32x4*)&W1g[qt * 16 + quad * 4];
#pragma unroll
        for (int e = 0; e < 4; ++e) {
            const int q = qt * 16 + quad * 4 + e;
            v3pC[qt * 4 + e] = __shfl(sp, q);
            v3mC[qt * 4 + e] = __shfl(sm, q);
            w1C[qt * 4 + e]  = w1v[e];
        }
    }

    // u[p=lane] = W5b @ W7[:,p] -> uS (wave-private LDS)
    {
        float u = 0.f;
#pragma unroll
        for (int c = 0; c < 16; ++c) {
            f32x4 w5v = *(const f32x4*)&W5g[64 + c * 4];
#pragma unroll
            for (int e = 0; e < 4; ++e) u += w5v[e] * W7g[(c * 4 + e) * 64 + lane];
        }
        uS[lane] = u;
    }

    // W2 A-fragments (bf16 hi only -- w2l is dead with pass1 gone)
    bf16x8 w2h[4][2];
#pragma unroll
    for (int qt = 0; qt < 4; ++qt)
#pragma unroll
        for (int s = 0; s < 2; ++s) {
            const float* src = &W2g[(qt * 16 + l15) * 64 + s * 32 + quad * 8];
            f32x4 f0 = *(const f32x4*)src;
            f32x4 f1 = *(const f32x4*)(src + 4);
            bf16x8 h;
#pragma unroll
            for (int e = 0; e < 4; ++e) { h[e] = (bf16)f0[e]; h[4 + e] = (bf16)f1[e]; }
            w2h[qt][s] = h;
        }

    // ---------------- mu1 = relu(base), exact fp32; accumulate smv ----------------
    float smv[16];
#pragma unroll
    for (int i = 0; i < 16; ++i) smv[i] = 0.f;
#pragma unroll
    for (int kt = 0; kt < 8; ++kt) {
        const int row = (kt * 16 + l15) * 64;
#pragma unroll
        for (int qt = 0; qt < 4; ++qt) {
            bf16x4 h;
#pragma unroll
            for (int e = 0; e < 4; ++e) {
                float t = fmaf(xk[kt], w1C[qt * 4 + e],
                          fmaf(apk[kt], v3pC[qt * 4 + e], bnk[kt] * v3mC[qt * 4 + e]));
                float v = fmaxf(t, 0.f);
                smv[qt * 4 + e] += v;
                h[e] = (bf16)v;
            }
            *(bf16x4*)&muS[row + ((2 * qt + (quad >> 1)) ^ sw) * 8 + 4 * (quad & 1)] = h;
        }
    }

    // ---------------- 3 iterations, zero barriers ----------------
    const f32x4 zero4 = {0.f, 0.f, 0.f, 0.f};
    const bf16x8 zero8 = {(bf16)0.f,(bf16)0.f,(bf16)0.f,(bf16)0.f,
                          (bf16)0.f,(bf16)0.f,(bf16)0.f,(bf16)0.f};
    for (int it = 0; it < 3; ++it) {
        // sumMu: l15 butterfly + publish to smS (wave-private; lgkmcnt by compiler)
#pragma unroll
        for (int m = 1; m <= 8; m <<= 1)
#pragma unroll
            for (int i = 0; i < 16; ++i) smv[i] += __shfl_xor(smv[i], m);
        if (l15 == 0) {
#pragma unroll
            for (int qt = 0; qt < 4; ++qt) {
                f32x4 v = {smv[qt * 4], smv[qt * 4 + 1], smv[qt * 4 + 2], smv[qt * 4 + 3]};
                *(f32x4*)&smS[qt * 16 + quad * 4] = v;
            }
        }
        // s2 = W2·sumMu by MFMA (R13-verified): B-frag with Sh in col n=0,
        // Sl in col n=1; 2 chained hi-W2 MFMAs per qt; extract cols 0+1.
        f32x4 s2q[4];
        {
            f32x4 p00 = *(const f32x4*)&smS[quad * 8];
            f32x4 p01 = *(const f32x4*)&smS[quad * 8 + 4];
            f32x4 p10 = *(const f32x4*)&smS[32 + quad * 8];
            f32x4 p11 = *(const f32x4*)&smS[32 + quad * 8 + 4];
            bf16x8 h0, l0, h1, l1;
#pragma unroll
            for (int e = 0; e < 4; ++e) {
                bf16 a = (bf16)p00[e], c = (bf16)p01[e];
                h0[e] = a; h0[4 + e] = c;
                l0[e]     = (bf16)(p00[e] - (float)a);
                l0[4 + e] = (bf16)(p01[e] - (float)c);
                bf16 d = (bf16)p10[e], f = (bf16)p11[e];
                h1[e] = d; h1[4 + e] = f;
                l1[e]     = (bf16)(p10[e] - (float)d);
                l1[4 + e] = (bf16)(p11[e] - (float)f);
            }
            bf16x8 bs0 = (l15 == 0) ? h0 : ((l15 == 1) ? l0 : zero8);
            bf16x8 bs1 = (l15 == 0) ? h1 : ((l15 == 1) ? l1 : zero8);
#pragma unroll
            for (int qt = 0; qt < 4; ++qt) {
                f32x4 a = MFMA16(w2h[qt][0], bs0, zero4);
                a = MFMA16(w2h[qt][1], bs1, a);
#pragma unroll
                for (int e = 0; e < 4; ++e)
                    s2q[qt][e] = __shfl(a[e], quad * 16) + __shfl(a[e], quad * 16 + 1);
            }
        }

        // main pass: 64 MFMAs + fused epilogue (base recomputed fp32-exact)
#pragma unroll
        for (int i = 0; i < 16; ++i) smv[i] = 0.f;
#pragma unroll
        for (int kt = 0; kt < 8; ++kt) {
            const int row = (kt * 16 + l15) * 64;
            bf16x8 m0 = *(const bf16x8*)&muS[row + ((quad) ^ sw) * 8];
            bf16x8 m1 = *(const bf16x8*)&muS[row + ((4 + quad) ^ sw) * 8];
#pragma unroll
            for (int qt = 0; qt < 4; ++qt) {
                f32x4 a = MFMA16(w2h[qt][0], m0, zero4);
                a = MFMA16(w2h[qt][1], m1, a);
                bf16x4 h;
#pragma unroll
                for (int e = 0; e < 4; ++e) {
                    float t = fmaf(xk[kt], w1C[qt * 4 + e], s2q[qt][e]);
                    t = fmaf(apk[kt], v3pC[qt * 4 + e], t);
                    t = fmaf(bnk[kt], v3mC[qt * 4 + e], t);
                    float v = fmaxf(t - a[e], 0.f);
                    smv[qt * 4 + e] += v;
                    h[e] = (bf16)v;
                }
                *(bf16x4*)&muS[row + ((2 * qt + (quad >> 1)) ^ sw) * 8 + 4 * (quad & 1)] = h;
            }
        }
    }

    // ---------------- readout (wave-internal) ----------------
#pragma unroll
    for (int m = 1; m <= 8; m <<= 1)
#pragma unroll
        for (int i = 0; i < 16; ++i) smv[i] += __shfl_xor(smv[i], m);
    if (l15 == 0) {
#pragma unroll
        for (int qt = 0; qt < 4; ++qt) {
            f32x4 v = {smv[qt * 4], smv[qt * 4 + 1], smv[qt * 4 + 2], smv[qt * 4 + 3]};
            *(f32x4*)&smS[qt * 16 + quad * 4] = v;
        }
    }

    float pl = 0.f;
#pragma unroll
    for (int c = 0; c < 16; ++c) {
        f32x4 sv = *(const f32x4*)&smS[c * 4];
        f32x4 w6 = *(const f32x4*)&W6g[lane * 64 + c * 4];
#pragma unroll
        for (int e = 0; e < 4; ++e) pl = fmaf(sv[e], w6[e], pl);
    }
    float qa = fmaxf(pl, 0.f) * W5g[lane];
#pragma unroll
    for (int m = 1; m < 64; m <<= 1) qa += __shfl_xor(qa, m);

    f32x4 uf[2][2];
#pragma unroll
    for (int s = 0; s < 2; ++s) {
        uf[s][0] = *(const f32x4*)&uS[s * 32 + quad * 8];
        uf[s][1] = *(const f32x4*)&uS[s * 32 + quad * 8 + 4];
    }

    float res[8];
#pragma unroll
    for (int kt = 0; kt < 8; ++kt) {
        const int row = (kt * 16 + l15) * 64;
        bf16x8 m0 = *(const bf16x8*)&muS[row + ((quad) ^ sw) * 8];
        bf16x8 m1 = *(const bf16x8*)&muS[row + ((4 + quad) ^ sw) * 8];
        float r = 0.f;
#pragma unroll
        for (int j = 0; j < 4; ++j) {
            r = fmaf((float)m0[j],     uf[0][0][j], r);
            r = fmaf((float)m0[4 + j], uf[0][1][j], r);
            r = fmaf((float)m1[j],     uf[1][0][j], r);
            r = fmaf((float)m1[4 + j], uf[1][1][j], r);
        }
        r += __shfl_xor(r, 16); r += __shfl_xor(r, 32);
        res[kt] = r;
    }
    float rA0 = (quad & 1) ? res[1] : res[0];
    float rA1 = (quad & 1) ? res[3] : res[2];
    float rA  = (quad & 2) ? rA1 : rA0;
    float rB0 = (quad & 1) ? res[5] : res[4];
    float rB1 = (quad & 1) ? res[7] : res[6];
    float rB  = (quad & 2) ? rB1 : rB0;
    Outg[b * 128 + lane]      = qa + rA;   // k = lane       (kt = quad)
    Outg[b * 128 + 64 + lane] = qa + rB;   // k = lane + 64  (kt = quad + 4)
}

extern "C" void kernel_launch(void* const* d_in, const int* in_sizes, int n_in,
                              void* d_out, int out_size, void* d_ws, size_t ws_size,
                              hipStream_t stream) {
    (void)n_in; (void)d_ws; (void)ws_size; (void)out_size;
    const int B = in_sizes[0] >> 7;   // 4096
    qnet_kernel<<<B, 64, 0, stream>>>(
        (const float*)d_in[0], (const float*)d_in[1], (const float*)d_in[2],
        (const float*)d_in[3], (const float*)d_in[4], (const float*)d_in[5],
        (const float*)d_in[6], (const float*)d_in[7], (const float*)d_in[8],
        (float*)d_out);
}